// Round 1
// baseline (239.483 us; speedup 1.0000x reference)
//
#include <hip/hip_runtime.h>

// Problem constants (B,N,C) = (32,1024,768), H=32
#define BB 32
#define NN 1024
#define CC 768
#define HH 32
#define NCHUNK 32
#define NPER (NN / NCHUNK)   // 32 rows per chunk
#define C4 (CC / 4)          // 192 float4 per row

// ---------------------------------------------------------------------------
// K1: per-(b, n-chunk) partial column sums: part[b*NCHUNK+ch][c] = sum_n x[b,n,c]
// ---------------------------------------------------------------------------
__global__ void pool_partial(const float* __restrict__ x, float* __restrict__ part) {
    const int blk = blockIdx.x;              // b*NCHUNK + ch
    const int b   = blk / NCHUNK;
    const int ch  = blk % NCHUNK;
    const int tid = threadIdx.x;
    const float* xb = x + ((size_t)b * NN + (size_t)ch * NPER) * CC;
    float* pb = part + (size_t)blk * CC;
#pragma unroll
    for (int cc = 0; cc < 3; ++cc) {
        const int c = cc * 256 + tid;
        float s = 0.f;
#pragma unroll 4
        for (int n = 0; n < NPER; ++n) s += xb[(size_t)n * CC + c];
        pb[c] = s;
    }
}

// ---------------------------------------------------------------------------
// K2: alpha[b][k] = (1/N) * sum_c pooled_sum[b][c] * W[k][c] + bias[k]
// one block per b, 256 threads
// ---------------------------------------------------------------------------
__global__ void alpha_kernel(const float* __restrict__ part,
                             const float* __restrict__ W,
                             const float* __restrict__ bias,
                             float* __restrict__ alpha) {
    const int b = blockIdx.x;
    const int tid = threadIdx.x;
    float ak[4] = {0.f, 0.f, 0.f, 0.f};
#pragma unroll
    for (int cc = 0; cc < 3; ++cc) {
        const int c = cc * 256 + tid;
        float s = 0.f;
#pragma unroll 8
        for (int ch = 0; ch < NCHUNK; ++ch)
            s += part[((size_t)b * NCHUNK + ch) * CC + c];
#pragma unroll
        for (int k = 0; k < 4; ++k) ak[k] += s * W[k * CC + c];
    }
    // block reduction: wave64 shuffle, then LDS across 4 waves
    const int lane = tid & 63;
    const int wid  = tid >> 6;
    __shared__ float red[4][4];  // [wave][k]
#pragma unroll
    for (int k = 0; k < 4; ++k) {
        float v = ak[k];
#pragma unroll
        for (int off = 32; off >= 1; off >>= 1) v += __shfl_down(v, off);
        if (lane == 0) red[wid][k] = v;
    }
    __syncthreads();
    if (tid < 4) {
        const float s = red[0][tid] + red[1][tid] + red[2][tid] + red[3][tid];
        alpha[b * 4 + tid] = s * (1.0f / (float)NN) + bias[tid];
    }
}

// ---------------------------------------------------------------------------
// K3: out[b,l,c] = a0*x[b,l,c] + a1*x[b,lt,c] + a2*x[b,1023-l,c] + a3*x[b,1023-lt,c]
// float4 grid-stride
// ---------------------------------------------------------------------------
__global__ void merge(const float* __restrict__ x,
                      const float* __restrict__ alpha,
                      float* __restrict__ out) {
    const unsigned total = (unsigned)BB * NN * C4;   // 6,291,456
    const float4* __restrict__ x4 = (const float4*)x;
    float4* __restrict__ o4 = (float4*)out;
    for (unsigned idx = blockIdx.x * blockDim.x + threadIdx.x; idx < total;
         idx += gridDim.x * blockDim.x) {
        const unsigned c4 = idx % C4;
        const unsigned l  = (idx / C4) % NN;
        const unsigned b  = idx / (C4 * NN);
        const unsigned lt  = ((l & (HH - 1)) << 5) | (l >> 5);
        const unsigned lr  = (NN - 1) - l;
        const unsigned ltr = (NN - 1) - lt;
        const float4* xb = x4 + (size_t)b * NN * C4;
        const float a0 = alpha[b * 4 + 0];
        const float a1 = alpha[b * 4 + 1];
        const float a2 = alpha[b * 4 + 2];
        const float a3 = alpha[b * 4 + 3];
        const float4 v0 = xb[(size_t)l   * C4 + c4];
        const float4 v1 = xb[(size_t)lt  * C4 + c4];
        const float4 v2 = xb[(size_t)lr  * C4 + c4];
        const float4 v3 = xb[(size_t)ltr * C4 + c4];
        float4 r;
        r.x = a0 * v0.x + a1 * v1.x + a2 * v2.x + a3 * v3.x;
        r.y = a0 * v0.y + a1 * v1.y + a2 * v2.y + a3 * v3.y;
        r.z = a0 * v0.z + a1 * v1.z + a2 * v2.z + a3 * v3.z;
        r.w = a0 * v0.w + a1 * v1.w + a2 * v2.w + a3 * v3.w;
        o4[idx] = r;
    }
}

extern "C" void kernel_launch(void* const* d_in, const int* in_sizes, int n_in,
                              void* d_out, int out_size, void* d_ws, size_t ws_size,
                              hipStream_t stream) {
    const float* x    = (const float*)d_in[0];   // (B,N,C) fp32
    const float* W    = (const float*)d_in[1];   // (4,C)   fp32
    const float* bias = (const float*)d_in[2];   // (4,)    fp32
    float* out = (float*)d_out;

    float* part  = (float*)d_ws;                           // B*NCHUNK*C floats = 3 MiB
    float* alpha = part + (size_t)BB * NCHUNK * CC;        // B*4 floats

    pool_partial<<<BB * NCHUNK, 256, 0, stream>>>(x, part);
    alpha_kernel<<<BB, 256, 0, stream>>>(part, W, bias, alpha);
    merge<<<2048, 256, 0, stream>>>(x, alpha, out);
}

// Round 3
// 197.286 us; speedup vs baseline: 1.2139x; 1.2139x over previous
//
#include <hip/hip_runtime.h>

// Problem constants (B,N,C) = (32,1024,768), H=32
#define BB 32
#define NN 1024
#define CC 768
#define HH 32
#define NCHUNK 32
#define NPER (NN / NCHUNK)   // 32 rows per chunk
#define C4 (CC / 4)          // 192 float4 per row

typedef float f32x4 __attribute__((ext_vector_type(4)));

__device__ __forceinline__ f32x4 f4_fma4(float a0, f32x4 v0, float a1, f32x4 v1,
                                         float a2, f32x4 v2, float a3, f32x4 v3) {
    return a0 * v0 + a1 * v1 + a2 * v2 + a3 * v3;
}

// ---------------------------------------------------------------------------
// K1: part[b*NCHUNK+ch][c4] = sum over 32 rows of x[b, ch*32+n, c4]  (float4)
// grid: BB*NCHUNK blocks x 192 threads
// ---------------------------------------------------------------------------
__global__ void pool_partial(const f32x4* __restrict__ x4, f32x4* __restrict__ part4) {
    const int blk = blockIdx.x;          // b*NCHUNK + ch
    const int b   = blk >> 5;
    const int ch  = blk & 31;
    const int t   = threadIdx.x;         // 0..191 (c4)
    const f32x4* xb = x4 + ((size_t)(b * NN + ch * NPER)) * C4 + t;
    f32x4 s = {0.f, 0.f, 0.f, 0.f};
#pragma unroll 8
    for (int n = 0; n < NPER; ++n) s += xb[(size_t)n * C4];
    part4[(size_t)blk * C4 + t] = s;
}

// ---------------------------------------------------------------------------
// K2: alpha[b][k] = (1/N) * sum_c pooled_sum[b][c] * W[k][c] + bias[k]
// grid: BB blocks x 192 threads
// ---------------------------------------------------------------------------
__global__ void alpha_kernel(const f32x4* __restrict__ part4,
                             const f32x4* __restrict__ W4,
                             const float* __restrict__ bias,
                             float* __restrict__ alpha) {
    const int b = blockIdx.x;
    const int t = threadIdx.x;           // 0..191 (c4)
    f32x4 s = {0.f, 0.f, 0.f, 0.f};
#pragma unroll 8
    for (int ch = 0; ch < NCHUNK; ++ch)
        s += part4[((size_t)(b * NCHUNK + ch)) * C4 + t];
    float ak[4];
#pragma unroll
    for (int k = 0; k < 4; ++k) {
        const f32x4 w = W4[k * C4 + t];
        ak[k] = s.x * w.x + s.y * w.y + s.z * w.z + s.w * w.w;
    }
    // reduce across 192 threads = 3 waves
    const int lane = t & 63;
    const int wid  = t >> 6;
    __shared__ float red[3][4];
#pragma unroll
    for (int k = 0; k < 4; ++k) {
        float v = ak[k];
#pragma unroll
        for (int off = 32; off >= 1; off >>= 1) v += __shfl_down(v, off);
        if (lane == 0) red[wid][k] = v;
    }
    __syncthreads();
    if (t < 4) {
        const float s3 = red[0][t] + red[1][t] + red[2][t];
        alpha[b * 4 + t] = s3 * (1.0f / (float)NN) + bias[t];
    }
}

// ---------------------------------------------------------------------------
// K3: orbit merge. Rows form Klein-4 orbits {l, T(l), R(l), TR(l)} closed under
// the 4 source transforms. One block per canonical orbit loads the 4 rows and
// writes all 4 output rows as permuted combinations -> exact 1x read, 1x write.
// grid: BB*NN blocks x 192 threads (non-canonical blocks exit immediately)
// ---------------------------------------------------------------------------
__global__ void merge(const f32x4* __restrict__ x4,
                      const float* __restrict__ alpha,
                      f32x4* __restrict__ o4) {
    const int b = blockIdx.x >> 10;
    const int l = blockIdx.x & 1023;
    const int lt  = ((l & (HH - 1)) << 5) | (l >> 5);   // transpose
    const int lr  = (NN - 1) - l;                       // reverse
    const int ltr = (NN - 1) - lt;                      // transpose+reverse
    if (lt < l || lr < l || ltr < l) return;            // canonical rep only

    const int t = threadIdx.x;                          // 0..191 (c4)
    const f32x4* xb = x4 + (size_t)b * (NN * C4);
    f32x4* ob = o4 + (size_t)b * (NN * C4);
    const float a0 = alpha[b * 4 + 0];
    const float a1 = alpha[b * 4 + 1];
    const float a2 = alpha[b * 4 + 2];
    const float a3 = alpha[b * 4 + 3];

    const f32x4 v0 = xb[(size_t)l   * C4 + t];
    const f32x4 v1 = xb[(size_t)lt  * C4 + t];
    const f32x4 v2 = xb[(size_t)lr  * C4 + t];
    const f32x4 v3 = xb[(size_t)ltr * C4 + t];

    // out[row] = a0*x[row] + a1*x[T(row)] + a2*x[R(row)] + a3*x[TR(row)]
    __builtin_nontemporal_store(f4_fma4(a0, v0, a1, v1, a2, v2, a3, v3), &ob[(size_t)l   * C4 + t]);
    __builtin_nontemporal_store(f4_fma4(a0, v1, a1, v0, a2, v3, a3, v2), &ob[(size_t)lt  * C4 + t]);
    __builtin_nontemporal_store(f4_fma4(a0, v2, a1, v3, a2, v0, a3, v1), &ob[(size_t)lr  * C4 + t]);
    __builtin_nontemporal_store(f4_fma4(a0, v3, a1, v2, a2, v1, a3, v0), &ob[(size_t)ltr * C4 + t]);
}

extern "C" void kernel_launch(void* const* d_in, const int* in_sizes, int n_in,
                              void* d_out, int out_size, void* d_ws, size_t ws_size,
                              hipStream_t stream) {
    const float* x    = (const float*)d_in[0];   // (B,N,C) fp32
    const float* W    = (const float*)d_in[1];   // (4,C)   fp32
    const float* bias = (const float*)d_in[2];   // (4,)    fp32
    float* out = (float*)d_out;

    float* part  = (float*)d_ws;                           // B*NCHUNK*C floats = 3 MiB
    float* alpha = part + (size_t)BB * NCHUNK * CC;        // B*4 floats

    pool_partial<<<BB * NCHUNK, 192, 0, stream>>>((const f32x4*)x, (f32x4*)part);
    alpha_kernel<<<BB, 192, 0, stream>>>((const f32x4*)part, (const f32x4*)W, bias, alpha);
    merge<<<BB * NN, 192, 0, stream>>>((const f32x4*)x, alpha, (f32x4*)out);
}

// Round 4
// 195.016 us; speedup vs baseline: 1.2280x; 1.0116x over previous
//
#include <hip/hip_runtime.h>

// Problem constants (B,N,C) = (32,1024,768), H=32
#define BB 32
#define NN 1024
#define CC 768
#define HH 32
#define NCHUNK 32
#define NPER (NN / NCHUNK)     // 32 rows per chunk
#define C4 (CC / 4)            // 192 float4 per row
#define NORB 272               // canonical orbits per batch: r<=c, r<=15, r+c<=31
#define OPB 2                  // orbits per merge block
#define MBLK (NORB / OPB)      // 136 merge blocks per batch

typedef float f32x4 __attribute__((ext_vector_type(4)));

// ---------------------------------------------------------------------------
// K1: fused pool + W-dot. For each (b, n-chunk of 32 rows):
//   s[c] = sum_{n in chunk} x[b,n,c]  (held across 192 threads as f32x4)
//   partW[b][ch][k] = sum_c s[c] * W[k][c]        (4 floats per block)
// grid: BB*NCHUNK blocks x 192 threads
// ---------------------------------------------------------------------------
__global__ void pool_dot(const f32x4* __restrict__ x4,
                         const f32x4* __restrict__ W4,
                         f32x4* __restrict__ partW4) {
    const int blk = blockIdx.x;          // b*NCHUNK + ch
    const int t   = threadIdx.x;         // 0..191 (c4)
    const f32x4* xb = x4 + (size_t)blk * (NPER * C4) + t;
    f32x4 s = {0.f, 0.f, 0.f, 0.f};
#pragma unroll 8
    for (int n = 0; n < NPER; ++n) s += xb[(size_t)n * C4];

    float d[4];
#pragma unroll
    for (int k = 0; k < 4; ++k) {
        const f32x4 w = W4[k * C4 + t];
        d[k] = s.x * w.x + s.y * w.y + s.z * w.z + s.w * w.w;
    }
    // reduce across 192 threads = 3 waves
    const int lane = t & 63;
    const int wid  = t >> 6;
    __shared__ float red[3][4];
#pragma unroll
    for (int k = 0; k < 4; ++k) {
        float v = d[k];
#pragma unroll
        for (int off = 32; off >= 1; off >>= 1) v += __shfl_down(v, off);
        if (lane == 0) red[wid][k] = v;
    }
    __syncthreads();
    if (t == 0) {
        f32x4 w;
        w.x = red[0][0] + red[1][0] + red[2][0];
        w.y = red[0][1] + red[1][1] + red[2][1];
        w.z = red[0][2] + red[1][2] + red[2][2];
        w.w = red[0][3] + red[1][3] + red[2][3];
        partW4[blk] = w;
    }
}

// ---------------------------------------------------------------------------
// K2: orbit merge. Rows form Klein-4 orbits {l, T(l), R(l), TR(l)} closed under
// the 4 source transforms (T=2D transpose of l in 32x32, R=reverse). Canonical
// reps: l=r*32+c with r<=c, r<=15, r+c<=31 -> 272 orbits/b, enumerated directly
// (no dead blocks). Each block: 2 orbits, 8 row-loads in flight, computes alpha
// from the 32 per-chunk W-dots (512B, L2-hot, broadcast), writes all rows once.
// grid: BB*MBLK blocks x 192 threads
// ---------------------------------------------------------------------------
__global__ void merge(const f32x4* __restrict__ x4,
                      const f32x4* __restrict__ partW4,
                      const f32x4* __restrict__ bias4,
                      f32x4* __restrict__ o4) {
    const int bidx = blockIdx.x;
    const int b = bidx / MBLK;
    const int j = bidx - b * MBLK;

    // alpha[b] = (1/N) * sum_ch partW[b][ch][:] + bias  (uniform across block)
    f32x4 acc = {0.f, 0.f, 0.f, 0.f};
#pragma unroll 8
    for (int ch = 0; ch < NCHUNK; ++ch) acc += partW4[b * NCHUNK + ch];
    const f32x4 al = acc * (1.0f / (float)NN) + bias4[0];
    const float a0 = al.x, a1 = al.y, a2 = al.z, a3 = al.w;

    const int t = threadIdx.x;           // 0..191 (c4)
    const f32x4* xb = x4 + (size_t)b * (NN * C4);
    f32x4* ob = o4 + (size_t)b * (NN * C4);

#pragma unroll
    for (int q = 0; q < OPB; ++q) {
        const int o = OPB * j + q;       // canonical orbit index 0..271
        // invert S(r) = r*(33-r): r = max rr with S(rr) <= o, then c = r + o - S(r)
        int r = 0;
#pragma unroll
        for (int rr = 1; rr <= 15; ++rr) if (rr * (33 - rr) <= o) r = rr;
        const int c = r + (o - r * (33 - r));
        const int l   = r * HH + c;
        const int lt  = c * HH + r;                // transpose
        const int lr  = (NN - 1) - l;              // reverse
        const int ltr = (NN - 1) - lt;             // transpose+reverse

        const f32x4 v0 = xb[(size_t)l   * C4 + t];
        const f32x4 v1 = xb[(size_t)lt  * C4 + t];
        const f32x4 v2 = xb[(size_t)lr  * C4 + t];
        const f32x4 v3 = xb[(size_t)ltr * C4 + t];

        // out[row] = a0*x[row] + a1*x[T(row)] + a2*x[R(row)] + a3*x[TR(row)]
        ob[(size_t)l   * C4 + t] = a0 * v0 + a1 * v1 + a2 * v2 + a3 * v3;
        ob[(size_t)lt  * C4 + t] = a0 * v1 + a1 * v0 + a2 * v3 + a3 * v2;
        ob[(size_t)lr  * C4 + t] = a0 * v2 + a1 * v3 + a2 * v0 + a3 * v1;
        ob[(size_t)ltr * C4 + t] = a0 * v3 + a1 * v2 + a2 * v1 + a3 * v0;
    }
}

extern "C" void kernel_launch(void* const* d_in, const int* in_sizes, int n_in,
                              void* d_out, int out_size, void* d_ws, size_t ws_size,
                              hipStream_t stream) {
    const float* x    = (const float*)d_in[0];   // (B,N,C) fp32
    const float* W    = (const float*)d_in[1];   // (4,C)   fp32
    const float* bias = (const float*)d_in[2];   // (4,)    fp32
    float* out = (float*)d_out;

    f32x4* partW = (f32x4*)d_ws;                 // BB*NCHUNK f32x4 = 16 KB

    pool_dot<<<BB * NCHUNK, 192, 0, stream>>>((const f32x4*)x, (const f32x4*)W, partW);
    merge<<<BB * MBLK, 192, 0, stream>>>((const f32x4*)x, partW,
                                         (const f32x4*)bias, (f32x4*)out);
}